// Round 5
// baseline (417.312 us; speedup 1.0000x reference)
//
#include <hip/hip_runtime.h>
#include <math.h>

#define DIM  64
#define HID  128
#define KNN  16
#define SEG  1024   // candidates per wave-segment (NPB/4)
#define TSZ  128    // position tile size per segment
#define CAP  12     // per-thread LDS candidate buffer capacity

typedef unsigned long long u64;
#define INF_BITS 0x7F800000u

// Insert (d,g) into ascending-sorted (bd,bi), dropping old max.
// Strict < on value keeps earlier-index entries first among equals — combined
// with index-ascending scan/buffer/merge order this reproduces top_k's
// stable (d, idx) lex rule exactly.
__device__ __forceinline__ void ins16(float (&bd)[KNN], int (&bi)[KNN],
                                      float d, int g) {
    float cd = d; int ci = g;
    #pragma unroll
    for (int i = 0; i < KNN; ++i) {
        bool lt = cd < bd[i];
        float dl = lt ? cd : bd[i];
        float dh = lt ? bd[i] : cd;
        int   il = lt ? ci : bi[i];
        int   ih = lt ? bi[i] : ci;
        bd[i] = dl; bi[i] = il; cd = dh; ci = ih;
    }
}

__device__ __forceinline__ void drain_buf(const u64* bufe, int tid,
        float (&bd)[KNN], int (&bi)[KNN], int& cnt,
        unsigned* thrU, int l) {
    for (int t = 0; t < CAP; ++t) {
        if (__ballot(t < cnt) == 0ull) break;
        u64 e = bufe[t * 256 + tid];
        float d = __uint_as_float((unsigned)e);
        int   g = (int)(e >> 32);
        if ((t < cnt) && (d < bd[KNN - 1])) ins16(bd, bi, d, g);
    }
    cnt = 0;
    // publish tightened per-query threshold (uint order == float order, d2>=0)
    atomicMin(&thrU[l], __float_as_uint(bd[KNN - 1]));
}

// float2 helpers, contraction OFF (bit-match numpy's mul/add sequence).
struct f2 { float a, b; };
__device__ __forceinline__ f2 f2mul(f2 x, float s) {
    #pragma clang fp contract(off)
    f2 r; r.a = x.a * s; r.b = x.b * s; return r;
}
__device__ __forceinline__ f2 f2add(f2 x, f2 y) {
    #pragma clang fp contract(off)
    f2 r; r.a = x.a + y.a; r.b = x.b + y.b; return r;
}
__device__ __forceinline__ f2 f2adds(f2 x, float s) {
    #pragma clang fp contract(off)
    f2 r; r.a = s + x.a; r.b = s + x.b; return r;
}
__device__ __forceinline__ f2 f2sub(f2 x, f2 y) {
    #pragma clang fp contract(off)
    f2 r; r.a = x.a - y.a; r.b = x.b - y.b; return r;
}

// Per-wave segment scan with cross-wave shared threshold.
template<bool CHECK>
__device__ __forceinline__ void knn_scan(
    const float* __restrict__ pos, int bbase, int segbase, int qlocal, int l,
    float qx, float qy, float qz, float qs,
    float* tx, float* ty, float* tz, float* ts,
    u64* bufe, unsigned* thrU, volatile unsigned* thrv, int tid,
    float (&bd)[KNN], int (&bi)[KNN])
{
    #pragma clang fp contract(off)
    int cnt = 0;

    // tile 0 (wave-private region; in-wave DS ordering suffices)
    #pragma unroll
    for (int m = 0; m < 2; ++m) {
        int t = (m << 6) + l;
        int g = (bbase + segbase + t) * 3;
        float ax = pos[g], ay = pos[g + 1], az = pos[g + 2];
        tx[t] = ax; ty[t] = ay; tz[t] = az;
        ts[t] = (ax * ax + ay * ay) + az * az;
    }

    __syncthreads();   // thr[] init (by wave 0) visible to all waves

    // seed: first 16 candidates of own segment straight into the sorted set
    #pragma unroll
    for (int k = 0; k < KNN; ++k) { bd[k] = INFINITY; bi[k] = 0x7FFFFFFF; }
    for (int jj = 0; jj < KNN; ++jj) {
        float ax = tx[jj], ay = ty[jj], az = tz[jj], as = ts[jj];
        float dot = (ax * qx + ay * qy) + az * qz;
        float d2  = (qs + as) - 2.0f * dot;
        int cj = segbase + jj;
        if (cj == qlocal) d2 = INFINITY;
        ins16(bd, bi, d2, cj);
    }
    atomicMin(&thrU[l], __float_as_uint(bd[KNN - 1]));

    int jstart = KNN;
    for (int tb = 0; tb < SEG; tb += TSZ) {
        if (tb > 0) {
            #pragma unroll
            for (int m = 0; m < 2; ++m) {
                int t = (m << 6) + l;
                int g = (bbase + segbase + tb + t) * 3;
                float ax = pos[g], ay = pos[g + 1], az = pos[g + 2];
                tx[t] = ax; ty[t] = ay; tz[t] = az;
                ts[t] = (ax * ax + ay * ay) + az * az;
            }
        }
        for (int j = jstart; j < TSZ; j += 4) {
            float tl = __uint_as_float(thrv[l]);   // volatile: re-read each group
            float4 X = *(const float4*)(tx + j);
            float4 Y = *(const float4*)(ty + j);
            float4 Z = *(const float4*)(tz + j);
            float4 S = *(const float4*)(ts + j);
            const int c0 = segbase + tb + j;

            {   f2 Px = {X.x, X.y}, Py = {Y.x, Y.y}, Pz = {Z.x, Z.y}, Ps = {S.x, S.y};
                f2 dot = f2add(f2add(f2mul(Px, qx), f2mul(Py, qy)), f2mul(Pz, qz));
                f2 d2  = f2sub(f2adds(Ps, qs), f2mul(dot, 2.0f));
                if (CHECK) {
                    if (c0     == qlocal) d2.a = INFINITY;
                    if (c0 + 1 == qlocal) d2.b = INFINITY;
                }
                if (d2.a <= tl) {
                    bufe[cnt * 256 + tid] =
                        ((u64)(unsigned)c0 << 32) | __float_as_uint(d2.a); ++cnt; }
                if (d2.b <= tl) {
                    bufe[cnt * 256 + tid] =
                        ((u64)(unsigned)(c0 + 1) << 32) | __float_as_uint(d2.b); ++cnt; }
            }
            {   f2 Px = {X.z, X.w}, Py = {Y.z, Y.w}, Pz = {Z.z, Z.w}, Ps = {S.z, S.w};
                f2 dot = f2add(f2add(f2mul(Px, qx), f2mul(Py, qy)), f2mul(Pz, qz));
                f2 d2  = f2sub(f2adds(Ps, qs), f2mul(dot, 2.0f));
                if (CHECK) {
                    if (c0 + 2 == qlocal) d2.a = INFINITY;
                    if (c0 + 3 == qlocal) d2.b = INFINITY;
                }
                if (d2.a <= tl) {
                    bufe[cnt * 256 + tid] =
                        ((u64)(unsigned)(c0 + 2) << 32) | __float_as_uint(d2.a); ++cnt; }
                if (d2.b <= tl) {
                    bufe[cnt * 256 + tid] =
                        ((u64)(unsigned)(c0 + 3) << 32) | __float_as_uint(d2.b); ++cnt; }
            }

            if (__ballot(cnt >= CAP - 4) != 0ull)
                drain_buf(bufe, tid, bd, bi, cnt, thrU, l);
        }
        jstart = 0;
    }
    drain_buf(bufe, tid, bd, bi, cnt, thrU, l);
}

// Kernel 1: exact 16-NN + gather + aggregate. Writes h = x + sum(nb) to agg_out.
__global__ __launch_bounds__(256, 4) void knn_agg(
    const float* __restrict__ x, const float* __restrict__ pos,
    float* __restrict__ agg_out)
{
    // 33.3 KB LDS. Phase 1: tiles (8 KB) + thr (256 B) + u64 buffers (24 KB).
    // Phase 2 alias: md[64 slots][64 queries] f32 + midx ints (32 KB).
    // Phase 3 alias: mi2[16][64] ints (4 KB).
    __shared__ u64 smem[4160];

    const int tid = threadIdx.x;
    const int w   = tid >> 6;
    const int l   = tid & 63;

    const int qb     = blockIdx.x;          // 1024 blocks x 64 queries
    const int batch  = qb >> 6;
    const int bbase  = batch << 12;
    const int qlocal = ((qb & 63) << 6) + l;
    const int qglob  = bbase + qlocal;

    float* tilef = (float*)smem;            // 2048 floats
    float* tx = tilef + w * 512;
    float* ty = tx + TSZ;
    float* tz = tx + 2 * TSZ;
    float* ts = tx + 3 * TSZ;
    unsigned* thrU = (unsigned*)(tilef + 2048);       // 64 u32
    u64* bufe = smem + 1056;                          // 3072 u64

    if (tid < 64) thrU[tid] = INF_BITS;     // before the barrier inside knn_scan

    float qx, qy, qz, qs;
    {
        #pragma clang fp contract(off)
        qx = pos[3 * qglob + 0];
        qy = pos[3 * qglob + 1];
        qz = pos[3 * qglob + 2];
        qs = (qx * qx + qy * qy) + qz * qz;
    }

    float bd[KNN]; int bi[KNN];
    const int segbase = w << 10;
    const int wself   = (qb & 63) >> 4;
    if (w == wself)
        knn_scan<true >(pos, bbase, segbase, qlocal, l, qx, qy, qz, qs,
                        tx, ty, tz, ts, bufe, thrU, thrU, tid, bd, bi);
    else
        knn_scan<false>(pos, bbase, segbase, qlocal, l, qx, qy, qz, qs,
                        tx, ty, tz, ts, bufe, thrU, thrU, tid, bd, bi);

    __syncthreads();                         // phase-1 LDS dead; re-alias

    // per-wave lists -> md/midx, transposed [slot][query] (conflict-free)
    float* md  = (float*)smem;               // 4096 floats
    int*  midx = (int*)(smem + 2048);        // 4096 ints
    #pragma unroll
    for (int k = 0; k < KNN; ++k) {
        int slot = (w << 4) + k;
        md[slot * 64 + l]   = bd[k];
        midx[slot * 64 + l] = bi[k];
    }
    __syncthreads();

    // merge 4 sorted lists (slot order == index order) -> exact top-16
    if (tid < 64) {
        float bd2[KNN]; int bi2[KNN];
        #pragma unroll
        for (int k = 0; k < KNN; ++k) {      // wave-0 list is already sorted
            bd2[k] = md[k * 64 + tid];
            bi2[k] = midx[k * 64 + tid];
        }
        for (int c = KNN; c < 64; ++c) {
            float d = md[c * 64 + tid];
            int   g = midx[c * 64 + tid];
            if (d < bd2[KNN - 1]) ins16(bd2, bi2, d, g);
        }
        int* mi2 = (int*)smem;               // single-wave: reads above precede writes
        #pragma unroll
        for (int k = 0; k < KNN; ++k) mi2[k * 64 + tid] = bi2[k];
    }
    __syncthreads();

    // gather + aggregate: 4 threads/row, 16 cols each
    {
        const int* mi2 = (const int*)smem;
        const int r  = tid >> 2;
        const int p  = tid & 3;
        const int q  = (qb << 6) + r;
        const int cb = p << 4;

        int idxs[KNN];
        #pragma unroll
        for (int k = 0; k < KNN; ++k) idxs[k] = mi2[k * 64 + r];

        float4 a0 = *(const float4*)(x + (size_t)q * DIM + cb + 0);
        float4 a1 = *(const float4*)(x + (size_t)q * DIM + cb + 4);
        float4 a2 = *(const float4*)(x + (size_t)q * DIM + cb + 8);
        float4 a3 = *(const float4*)(x + (size_t)q * DIM + cb + 12);

        #pragma unroll 4
        for (int k = 0; k < KNN; ++k) {
            const float* nr = x + (size_t)(bbase + idxs[k]) * DIM + cb;
            float4 v0 = *(const float4*)(nr + 0);
            float4 v1 = *(const float4*)(nr + 4);
            float4 v2 = *(const float4*)(nr + 8);
            float4 v3 = *(const float4*)(nr + 12);
            a0.x += v0.x; a0.y += v0.y; a0.z += v0.z; a0.w += v0.w;
            a1.x += v1.x; a1.y += v1.y; a1.z += v1.z; a1.w += v1.w;
            a2.x += v2.x; a2.y += v2.y; a2.z += v2.z; a2.w += v2.w;
            a3.x += v3.x; a3.y += v3.y; a3.z += v3.z; a3.w += v3.w;
        }

        float* o = agg_out + (size_t)q * DIM + cb;
        *(float4*)(o + 0)  = a0;
        *(float4*)(o + 4)  = a1;
        *(float4*)(o + 8)  = a2;
        *(float4*)(o + 12) = a3;
    }
}

// prep: transpose W1 [64][128] -> w1t [128][64] in workspace (contiguous per j)
__global__ void prep(const float* __restrict__ W1, float* __restrict__ w1t) {
    int e = blockIdx.x * 256 + threadIdx.x;   // 8192 elems
    int k = e >> 7, j = e & 127;
    w1t[j * 64 + k] = W1[e];
}

// Kernel 2: out = relu(h @ W1 + b1) @ W2 + b2, in-place on io (= d_out).
// Thread-per-row; weights via wave-uniform scalar loads (s_load + v_fmac with
// SGPR operand) — no LDS, no barriers, pure-VALU. x row lives in 64 VGPRs.
__global__ __launch_bounds__(256, 1) void mlp(
    const float* __restrict__ w1t, const float* __restrict__ b1,
    const float* __restrict__ W2, const float* __restrict__ b2,
    float* __restrict__ io)
{
    const int row = blockIdx.x * 256 + threadIdx.x;

    float xv[DIM];
    {
        const float4* xr = (const float4*)(io + (size_t)row * DIM);
        #pragma unroll
        for (int i = 0; i < 16; ++i) {
            float4 v = xr[i];
            xv[4*i] = v.x; xv[4*i+1] = v.y; xv[4*i+2] = v.z; xv[4*i+3] = v.w;
        }
    }

    float acc[DIM];
    #pragma unroll
    for (int c = 0; c < DIM; ++c) acc[c] = b2[c];   // uniform -> scalar loads

    for (int j = 0; j < HID; ++j) {
        const float* w1 = w1t + j * DIM;            // uniform row
        float s0 = 0.f, s1 = 0.f, s2 = 0.f, s3 = 0.f;
        #pragma unroll
        for (int c = 0; c < DIM; c += 4) {
            s0 = fmaf(w1[c + 0], xv[c + 0], s0);
            s1 = fmaf(w1[c + 1], xv[c + 1], s1);
            s2 = fmaf(w1[c + 2], xv[c + 2], s2);
            s3 = fmaf(w1[c + 3], xv[c + 3], s3);
        }
        float h = fmaxf((s0 + s1) + (s2 + s3) + b1[j], 0.0f);

        const float* w2 = W2 + j * DIM;             // uniform row
        #pragma unroll
        for (int c = 0; c < DIM; ++c)
            acc[c] = fmaf(h, w2[c], acc[c]);
    }

    float4* o = (float4*)(io + (size_t)row * DIM);
    #pragma unroll
    for (int i = 0; i < 16; ++i)
        o[i] = make_float4(acc[4*i], acc[4*i+1], acc[4*i+2], acc[4*i+3]);
}

extern "C" void kernel_launch(void* const* d_in, const int* in_sizes, int n_in,
                              void* d_out, int out_size, void* d_ws, size_t ws_size,
                              hipStream_t stream) {
    (void)in_sizes; (void)n_in; (void)ws_size; (void)out_size;
    const float* x   = (const float*)d_in[0];
    const float* pos = (const float*)d_in[1];
    // d_in[2] = batch indices: deterministic (i // (N/B)), not needed
    const float* W1  = (const float*)d_in[3];
    const float* b1  = (const float*)d_in[4];
    const float* W2  = (const float*)d_in[5];
    const float* b2  = (const float*)d_in[6];
    float* out = (float*)d_out;
    float* w1t = (float*)d_ws;               // 32 KB scratch

    prep<<<dim3(32), dim3(256), 0, stream>>>(W1, w1t);
    knn_agg<<<dim3(1024), dim3(256), 0, stream>>>(x, pos, out);
    mlp<<<dim3(256), dim3(256), 0, stream>>>(w1t, b1, W2, b2, out);
}